// Round 6
// baseline (280.632 us; speedup 1.0000x reference)
//
#include <hip/hip_runtime.h>

// SpectralConv2d DHT spectral conv, B=16, Cin=Cout=64, H=W=128, modes 20x20.
// All stages linear; blurs folded into bases/weights.
//   fwd:  X(k1,k2) = sum_n1 [cos(th k1 n1) Pc - sin(th k1 n1) Ps
//                            - sin(th k1(n1+1)) Pc1 - cos(th k1(n1+1)) Ps1]
//   inv (rank-42): y(u,v) = sum_{A=0..20} cosb(u,A)*RsC[A][v] + sinb(u,A)*RsS[A][v]
// Kernels:
//  kinit(3 blocks): L2g/RB2g (42x128 inverse bases), Tg (128x40), Lf2g (20x512)
//  k0a: blur w1 over Cout + transpose -> wbT;  k0b: Wp/Wm combine
//  k1:  Pw = x * Tg   (register-blocked GEMM: 8x10 thread tiles, K-chunked LDS)
//  k2:  per (b,c): rotation -> Pm2[20][524], X1[m][bc] = Lf2g . Pm2
//  k2b: blur X1 over batch; k3: channel mix -> O[b,o,m]
//  k5b: per (b,o): Rs2[42][128] in LDS, Y = L2 * Rs2

#define TWO_PI 6.283185307179586f
#define THETA (TWO_PI / 128.0f)

__device__ __forceinline__ void gauss9(float* g) {
  float s = 0.f;
#pragma unroll
  for (int t = 0; t < 9; ++t) { float d = (float)(t - 4); g[t] = expf(-0.5f * d * d); s += g[t]; }
  float inv = 1.f / s;
#pragma unroll
  for (int t = 0; t < 9; ++t) g[t] *= inv;
}

// ---- kinit: b0: L2g+RB2g (42x128 each), b1: Tg, b2: Lf2g
__global__ void kinit(float* __restrict__ L2g, float* __restrict__ RB2g,
                      float* __restrict__ Tg, float* __restrict__ Lf2g) {
  __shared__ float raw[128][44];
  int tid = threadIdx.x;
  int blk = blockIdx.x;
  if (blk == 1) {
    for (int i = tid; i < 5120; i += 256) {
      int n2 = i / 40, col = i - n2 * 40;
      int k2 = (col < 20) ? col : col - 20;
      float a = (float)((k2 * n2) & 127) * THETA;
      Tg[i] = (col < 20) ? cosf(a) : sinf(a);
    }
    return;
  }
  if (blk == 2) {
    for (int i = tid; i < 10240; i += 256) {
      int k1 = i >> 9, t = i & 511;
      int q = t >> 7, n1 = t & 127;
      int nn = n1 + ((q >= 2) ? 1 : 0);
      float a = (float)((k1 * nn) & 127) * THETA;
      float v;
      if (q == 0) v = cosf(a);
      else if (q == 1) v = -sinf(a);
      else if (q == 2) v = -sinf(a);
      else v = -cosf(a);
      Lf2g[i] = v;
    }
    return;
  }
  // block 0: rank-42 bases. rows 0..20 = cos(th u A), 21..41 = sin(th u A)
  for (int i = tid; i < 5376; i += 256) {
    int u = i / 42, t = i - u * 42;
    int A = (t < 21) ? t : t - 21;
    float a = (float)((u * A) & 127) * THETA;
    raw[u][t] = (t < 21) ? cosf(a) : sinf(a);
  }
  __syncthreads();
  float g[9]; gauss9(g);
  for (int i = tid; i < 5376; i += 256) {
    int u = i / 42, t = i - u * 42;
    float acc = 0.f;
#pragma unroll
    for (int tp = 0; tp < 9; ++tp) {
      int uc = u - 4 + tp; uc = uc < 0 ? 0 : (uc > 127 ? 127 : uc);
      acc += g[tp] * raw[uc][t];
    }
    L2g[t * 128 + u] = acc;
    bool keep = (u <= 32) || (u >= 96);
    RB2g[t * 128 + u] = keep ? acc : 0.f;
  }
}

// ---- k0a: blur w1 over Cout + transpose: wbT[(c*400+m)*64+o]
__global__ void k0a_blurT(const float* __restrict__ w1, float* __restrict__ wbT) {
  __shared__ float tile[64][69];
  int c = blockIdx.x / 7, chunk = blockIdx.x % 7;
  int m0 = chunk * 64;
  int mw = 400 - m0; if (mw > 64) mw = 64;
  int tid = threadIdx.x;
  for (int t = tid; t < 4096; t += 256) {
    int o = t >> 6, mm = t & 63;
    tile[o][mm] = (mm < mw) ? w1[(c * 64 + o) * 400 + m0 + mm] : 0.f;
  }
  __syncthreads();
  float g[9]; gauss9(g);
  for (int t = tid; t < 4096; t += 256) {
    int mm = t >> 6, o = t & 63;
    if (mm >= mw) continue;
    float acc = 0.f;
#pragma unroll
    for (int tp = 0; tp < 9; ++tp) {
      int oc = o - 4 + tp; oc = oc < 0 ? 0 : (oc > 63 ? 63 : oc);
      acc += g[tp] * tile[oc][mm];
    }
    wbT[(c * 400 + m0 + mm) * 64 + o] = acc;
  }
}

// ---- k0b: Wp/Wm[(m*64+c)*64+o] = sc*(wbT[c][m][o] +/- wbT[c][nm][o])
__global__ void k0b_combine(const float* __restrict__ wbT, float* __restrict__ Wp,
                            float* __restrict__ Wm) {
  int m = blockIdx.x;
  int i = m / 20, j = m - i * 20;
  int nm = ((20 - i) % 20) * 20 + ((20 - j) % 20);
  int tid = threadIdx.x;
  const float sc = 0.5f / 16384.0f;
  for (int t = tid; t < 4096; t += 256) {
    int c = t >> 6, o = t & 63;
    float a = wbT[(c * 400 + m) * 64 + o];
    float b = wbT[(c * 400 + nm) * 64 + o];
    Wp[(m * 64 + c) * 64 + o] = (a + b) * sc;
    Wm[(m * 64 + c) * 64 + o] = (a - b) * sc;
  }
}

// ---- k1 v6: Pw[131072 rows][40] = x[rows][128] * Tg[128][40]
// 512 blocks x 128 threads; block = 256 rows; thread tile 8 rows x 10 cols (80 acc).
// K chunked x16 into LDS xs (stride 268 -> 2-way staging, broadcast compute reads).
// Tg staged to LDS once. Per K-step/thread: 2 b128 (A) + 5 b64 (B) per 80 FMA.
__global__ void __launch_bounds__(128) k1_rows(const float* __restrict__ x,
                                               const float* __restrict__ Tg,
                                               float* __restrict__ Pw) {
  __shared__ __align__(16) float xs[16 * 268];   // 17.2 KB
  __shared__ __align__(16) float ts[5120];       // 20.5 KB
  int tid = threadIdx.x;
  long row0 = (long)blockIdx.x * 256;
  const float4* tg4 = (const float4*)Tg;
  float4* ts4 = (float4*)ts;
  for (int t = tid; t < 1280; t += 128) ts4[t] = tg4[t];

  int rg = tid >> 2, cg = tid & 3;
  int r0 = rg * 8, c0 = cg * 10;
  float acc[8][10];
#pragma unroll
  for (int i = 0; i < 8; ++i)
#pragma unroll
    for (int j = 0; j < 10; ++j) acc[i][j] = 0.f;

  for (int ch = 0; ch < 8; ++ch) {
    __syncthreads();
    // stage 256 rows x 16 k: 1024 float4, 8 per thread
    for (int t = tid; t < 1024; t += 128) {
      int r = t >> 2, fq = t & 3;
      float4 v = *(const float4*)(x + (row0 + r) * 128 + ch * 16 + fq * 4);
      float vv[4] = {v.x, v.y, v.z, v.w};
#pragma unroll
      for (int j = 0; j < 4; ++j) xs[(fq * 4 + j) * 268 + r] = vv[j];
    }
    __syncthreads();
#pragma unroll 2
    for (int k = 0; k < 16; ++k) {
      float4 a0 = *(const float4*)&xs[k * 268 + r0];
      float4 a1 = *(const float4*)&xs[k * 268 + r0 + 4];
      const float* tb = ts + (ch * 16 + k) * 40 + c0;
      float2 b0 = *(const float2*)(tb + 0);
      float2 b1 = *(const float2*)(tb + 2);
      float2 b2 = *(const float2*)(tb + 4);
      float2 b3 = *(const float2*)(tb + 6);
      float2 b4 = *(const float2*)(tb + 8);
      float av[8] = {a0.x, a0.y, a0.z, a0.w, a1.x, a1.y, a1.z, a1.w};
      float bv[10] = {b0.x, b0.y, b1.x, b1.y, b2.x, b2.y, b3.x, b3.y, b4.x, b4.y};
#pragma unroll
      for (int i = 0; i < 8; ++i)
#pragma unroll
        for (int j = 0; j < 10; ++j) acc[i][j] += av[i] * bv[j];
    }
  }
#pragma unroll
  for (int i = 0; i < 8; ++i) {
    float* dst = Pw + (row0 + r0 + i) * 40 + c0;
#pragma unroll
    for (int j = 0; j < 5; ++j)
      *(float2*)(dst + 2 * j) = make_float2(acc[i][2 * j], acc[i][2 * j + 1]);
  }
}

// ---- k2: per (b,c): Pm2[20][524] (with rotation), X1[m][bc] = Lf2g . Pm2
__global__ void k2_modes(const float* __restrict__ Pw, const float* __restrict__ Lf2g,
                         float* __restrict__ X1) {
  __shared__ float Pm2[20][524];
  __shared__ float ct[128];
  int bc = blockIdx.x, tid = threadIdx.x;
  if (tid < 128) ct[tid] = cosf(THETA * (float)tid);
  const float4* src = (const float4*)(Pw + (long)bc * 5120);
  for (int t = tid; t < 1280; t += 256) {
    float4 v = src[t];
    int base = t * 4;
    int n1 = base / 40, col = base - 40 * n1;
    float vv[4] = {v.x, v.y, v.z, v.w};
#pragma unroll
    for (int j = 0; j < 4; ++j) {
      int cc = col + j;
      int k2 = (cc < 20) ? cc : cc - 20;
      int part = (cc < 20) ? 0 : 1;
      Pm2[k2][part * 128 + n1] = vv[j];
    }
  }
  __syncthreads();
  for (int t = tid; t < 2560; t += 256) {
    int k2 = t >> 7, n1 = t & 127;
    float pc = Pm2[k2][n1], ps = Pm2[k2][128 + n1];
    float ck = ct[k2], sk = ct[(k2 + 96) & 127];
    Pm2[k2][256 + n1] = ck * pc - sk * ps;
    Pm2[k2][384 + n1] = sk * pc + ck * ps;
  }
  __syncthreads();
  if (tid >= 100) return;
  int k1 = (tid / 10) * 2, k2 = (tid % 10) * 2;
  float a00 = 0.f, a01 = 0.f, a10 = 0.f, a11 = 0.f;
  for (int t = 0; t < 512; t += 4) {
    float4 l0 = *(const float4*)(Lf2g + k1 * 512 + t);
    float4 l1 = *(const float4*)(Lf2g + (k1 + 1) * 512 + t);
    float4 p0 = *(const float4*)&Pm2[k2][t];
    float4 p1 = *(const float4*)&Pm2[k2 + 1][t];
    a00 += l0.x * p0.x + l0.y * p0.y + l0.z * p0.z + l0.w * p0.w;
    a01 += l0.x * p1.x + l0.y * p1.y + l0.z * p1.z + l0.w * p1.w;
    a10 += l1.x * p0.x + l1.y * p0.y + l1.z * p0.z + l1.w * p0.w;
    a11 += l1.x * p1.x + l1.y * p1.y + l1.z * p1.z + l1.w * p1.w;
  }
  X1[(k1 * 20 + k2) * 1024 + bc] = a00;
  X1[(k1 * 20 + k2 + 1) * 1024 + bc] = a01;
  X1[((k1 + 1) * 20 + k2) * 1024 + bc] = a10;
  X1[((k1 + 1) * 20 + k2 + 1) * 1024 + bc] = a11;
}

// ---- k2b: blur over batch axis (16, clamp)
__global__ void k2b_blurB(const float* __restrict__ X1, float* __restrict__ X1b) {
  int idx = blockIdx.x * 256 + threadIdx.x;
  if (idx >= 400 * 16 * 64) return;
  int c = idx & 63, b = (idx >> 6) & 15, m = idx >> 10;
  float g[9]; gauss9(g);
  float acc = 0.f;
#pragma unroll
  for (int t = 0; t < 9; ++t) {
    int bb = b - 4 + t; bb = bb < 0 ? 0 : (bb > 15 ? 15 : bb);
    acc += g[t] * X1[m * 1024 + bb * 64 + c];
  }
  X1b[idx] = acc;
}

// ---- k3: one block per mode m; O[(b*64+o)*400 + m]
__global__ void k3_mix(const float* __restrict__ X1b, const float* __restrict__ Wp,
                       const float* __restrict__ Wm, float* __restrict__ O) {
  __shared__ float Xa[1024], Xn[1024];
  int m = blockIdx.x, tid = threadIdx.x;
  int i = m / 20, j = m - i * 20;
  int nm = ((20 - i) % 20) * 20 + ((20 - j) % 20);
  for (int t = tid; t < 1024; t += 256) {
    Xa[t] = X1b[m * 1024 + t];
    Xn[t] = X1b[nm * 1024 + t];
  }
  __syncthreads();
  int o = tid & 63, b0 = tid >> 6;
  float acc[4] = {0.f, 0.f, 0.f, 0.f};
  for (int c = 0; c < 64; ++c) {
    float wp = Wp[(m * 64 + c) * 64 + o];
    float wm = Wm[(m * 64 + c) * 64 + o];
#pragma unroll
    for (int q = 0; q < 4; ++q) {
      int b = b0 + q * 4;
      acc[q] += Xa[b * 64 + c] * wp + Xn[b * 64 + c] * wm;
    }
  }
#pragma unroll
  for (int q = 0; q < 4; ++q) {
    int b = b0 + q * 4;
    O[(b * 64 + o) * 400 + m] = acc[q];
  }
}

// ---- k5b: per (b,o): Rs2[42][128] (C rows 0..20, S rows 21..41), Y = L2 * Rs2
__global__ void __launch_bounds__(256) k5b_final(const float* __restrict__ O,
                                                 const float* __restrict__ L2g,
                                                 const float* __restrict__ RB2g,
                                                 float* __restrict__ out) {
  __shared__ float Os[400];
  __shared__ float Rs[42 * 128];
  int bo = blockIdx.x, tid = threadIdx.x;
  for (int t = tid; t < 400; t += 256) Os[t] = O[bo * 400 + t];
  __syncthreads();
  const float4* Bc4 = (const float4*)RB2g;             // rows 0..20
  const float4* Bs4 = (const float4*)(RB2g + 21 * 128);
  for (int task = tid; task < 1344; task += 256) {
    int r = task >> 5, vq = task & 31;
    bool isS = (r >= 21);
    int A = isS ? (r - 21) : r;
    float4 acc = make_float4(0.f, 0.f, 0.f, 0.f);
    if (A < 20) {
      const float4* Bm = isS ? Bs4 : Bc4;
      float sgn = isS ? -1.f : 1.f;
#pragma unroll
      for (int k2 = 0; k2 < 20; ++k2) {
        float ov = sgn * Os[A * 20 + k2];
        float4 b = Bm[k2 * 32 + vq];
        acc.x += ov * b.x; acc.y += ov * b.y; acc.z += ov * b.z; acc.w += ov * b.w;
      }
    }
    if (A >= 1) {
      const float4* Bm = isS ? Bc4 : Bs4;
#pragma unroll
      for (int k2 = 0; k2 < 20; ++k2) {
        float ov = Os[(A - 1) * 20 + k2];
        float4 b = Bm[(k2 + 1) * 32 + vq];
        acc.x -= ov * b.x; acc.y -= ov * b.y; acc.z -= ov * b.z; acc.w -= ov * b.w;
      }
    }
    *(float4*)&Rs[r * 128 + vq * 4] = acc;
  }
  __syncthreads();
  int ug = tid >> 4, vg = tid & 15;
  int u0 = ug * 8, v0 = vg * 4;   // v-cols: v0..v0+3 and 64+v0..64+v0+3
  float acc[8][8];
#pragma unroll
  for (int i = 0; i < 8; ++i)
#pragma unroll
    for (int j = 0; j < 8; ++j) acc[i][j] = 0.f;
  for (int r = 0; r < 42; ++r) {
    float4 a0 = *(const float4*)(L2g + r * 128 + u0);
    float4 a1 = *(const float4*)(L2g + r * 128 + u0 + 4);
    float4 b0 = *(const float4*)&Rs[r * 128 + v0];
    float4 b1 = *(const float4*)&Rs[r * 128 + 64 + v0];
    float av[8] = {a0.x, a0.y, a0.z, a0.w, a1.x, a1.y, a1.z, a1.w};
    float bv[8] = {b0.x, b0.y, b0.z, b0.w, b1.x, b1.y, b1.z, b1.w};
#pragma unroll
    for (int i = 0; i < 8; ++i)
#pragma unroll
      for (int j = 0; j < 8; ++j) acc[i][j] += av[i] * bv[j];
  }
  long base = (long)bo * 16384;
#pragma unroll
  for (int i = 0; i < 8; ++i) {
    float4 s0 = make_float4(acc[i][0], acc[i][1], acc[i][2], acc[i][3]);
    float4 s1 = make_float4(acc[i][4], acc[i][5], acc[i][6], acc[i][7]);
    *(float4*)&out[base + (u0 + i) * 128 + v0] = s0;
    *(float4*)&out[base + (u0 + i) * 128 + 64 + v0] = s1;
  }
}

extern "C" void kernel_launch(void* const* d_in, const int* in_sizes, int n_in,
                              void* d_out, int out_size, void* d_ws, size_t ws_size,
                              hipStream_t stream) {
  const float* x = (const float*)d_in[0];    // (16,64,128,128)
  const float* w1 = (const float*)d_in[1];   // (64,64,20,20)
  float* out = (float*)d_out;                // (16,64,128,128)
  float* ws = (float*)d_ws;

  float* Wp = ws;                  // 1,638,400
  float* Wm = Wp + 1638400;        // 1,638,400
  float* Pw = Wm + 1638400;        // 5,242,880
  float* X1 = Pw + 5242880;        // 409,600
  float* X1b = X1 + 409600;        // 409,600
  float* O = X1b + 409600;         // 409,600
  float* wbT = O + 409600;         // 1,638,400
  float* Tg = wbT + 1638400;       // 5,120
  float* Lf2g = Tg + 5120;         // 10,240
  float* L2g = Lf2g + 10240;       // 5,376
  float* RB2g = L2g + 5376;        // 5,376   (total ~45 MB)

  hipLaunchKernelGGL(kinit, dim3(3), dim3(256), 0, stream, L2g, RB2g, Tg, Lf2g);
  hipLaunchKernelGGL(k0a_blurT, dim3(448), dim3(256), 0, stream, w1, wbT);
  hipLaunchKernelGGL(k0b_combine, dim3(400), dim3(256), 0, stream, wbT, Wp, Wm);
  hipLaunchKernelGGL(k1_rows, dim3(512), dim3(128), 0, stream, x, Tg, Pw);
  hipLaunchKernelGGL(k2_modes, dim3(1024), dim3(256), 0, stream, Pw, Lf2g, X1);
  hipLaunchKernelGGL(k2b_blurB, dim3(1600), dim3(256), 0, stream, X1, X1b);
  hipLaunchKernelGGL(k3_mix, dim3(400), dim3(256), 0, stream, X1b, Wp, Wm, O);
  hipLaunchKernelGGL(k5b_final, dim3(1024), dim3(256), 0, stream, O, L2g, RB2g, out);
}

// Round 7
// 250.119 us; speedup vs baseline: 1.1220x; 1.1220x over previous
//
#include <hip/hip_runtime.h>

// SpectralConv2d DHT spectral conv, B=16, Cin=Cout=64, H=W=128, modes 20x20.
// All stages linear; blurs folded into bases/weights.
//   fwd:  X(k1,k2) = sum_n1 [cos(th k1 n1) Pc - sin(th k1 n1) Ps
//                            - sin(th k1(n1+1)) Pc1 - cos(th k1(n1+1)) Ps1]
//   inv (rank-42): y(u,v) = sum_{A=0..20} cosb(u,A)*RsC[A][v] + sinb(u,A)*RsS[A][v]
// Kernels:
//  kinit(3 blocks): L2g/RB2g (42x128 inverse bases), Tg (128x40), Lf2g (20x512)
//  k0a: blur w1 over Cout + transpose -> wbT;  k0b: Wp/Wm combine
//  k12: FUSED per (b,c): x-tile -> Pw (in Pm2 layout, LDS) -> rotation -> X1 modes
//  k3:  grid (m x 4 b-groups): batch-blur folded into staging; O[b,o,m]
//  k5b: per (b,o): Rs2[42][128] in LDS, Y = L2 * Rs2

#define TWO_PI 6.283185307179586f
#define THETA (TWO_PI / 128.0f)

__device__ __forceinline__ void gauss9(float* g) {
  float s = 0.f;
#pragma unroll
  for (int t = 0; t < 9; ++t) { float d = (float)(t - 4); g[t] = expf(-0.5f * d * d); s += g[t]; }
  float inv = 1.f / s;
#pragma unroll
  for (int t = 0; t < 9; ++t) g[t] *= inv;
}

// ---- kinit: b0: L2g+RB2g (42x128 each), b1: Tg, b2: Lf2g
__global__ void kinit(float* __restrict__ L2g, float* __restrict__ RB2g,
                      float* __restrict__ Tg, float* __restrict__ Lf2g) {
  __shared__ float raw[128][44];
  int tid = threadIdx.x;
  int blk = blockIdx.x;
  if (blk == 1) {
    for (int i = tid; i < 5120; i += 256) {
      int n2 = i / 40, col = i - n2 * 40;
      int k2 = (col < 20) ? col : col - 20;
      float a = (float)((k2 * n2) & 127) * THETA;
      Tg[i] = (col < 20) ? cosf(a) : sinf(a);
    }
    return;
  }
  if (blk == 2) {
    for (int i = tid; i < 10240; i += 256) {
      int k1 = i >> 9, t = i & 511;
      int q = t >> 7, n1 = t & 127;
      int nn = n1 + ((q >= 2) ? 1 : 0);
      float a = (float)((k1 * nn) & 127) * THETA;
      float v;
      if (q == 0) v = cosf(a);
      else if (q == 1) v = -sinf(a);
      else if (q == 2) v = -sinf(a);
      else v = -cosf(a);
      Lf2g[i] = v;
    }
    return;
  }
  // block 0: rank-42 bases. rows 0..20 = cos(th u A), 21..41 = sin(th u A)
  for (int i = tid; i < 5376; i += 256) {
    int u = i / 42, t = i - u * 42;
    int A = (t < 21) ? t : t - 21;
    float a = (float)((u * A) & 127) * THETA;
    raw[u][t] = (t < 21) ? cosf(a) : sinf(a);
  }
  __syncthreads();
  float g[9]; gauss9(g);
  for (int i = tid; i < 5376; i += 256) {
    int u = i / 42, t = i - u * 42;
    float acc = 0.f;
#pragma unroll
    for (int tp = 0; tp < 9; ++tp) {
      int uc = u - 4 + tp; uc = uc < 0 ? 0 : (uc > 127 ? 127 : uc);
      acc += g[tp] * raw[uc][t];
    }
    L2g[t * 128 + u] = acc;
    bool keep = (u <= 32) || (u >= 96);
    RB2g[t * 128 + u] = keep ? acc : 0.f;
  }
}

// ---- k0a: blur w1 over Cout + transpose: wbT[(c*400+m)*64+o]
__global__ void k0a_blurT(const float* __restrict__ w1, float* __restrict__ wbT) {
  __shared__ float tile[64][69];
  int c = blockIdx.x / 7, chunk = blockIdx.x % 7;
  int m0 = chunk * 64;
  int mw = 400 - m0; if (mw > 64) mw = 64;
  int tid = threadIdx.x;
  for (int t = tid; t < 4096; t += 256) {
    int o = t >> 6, mm = t & 63;
    tile[o][mm] = (mm < mw) ? w1[(c * 64 + o) * 400 + m0 + mm] : 0.f;
  }
  __syncthreads();
  float g[9]; gauss9(g);
  for (int t = tid; t < 4096; t += 256) {
    int mm = t >> 6, o = t & 63;
    if (mm >= mw) continue;
    float acc = 0.f;
#pragma unroll
    for (int tp = 0; tp < 9; ++tp) {
      int oc = o - 4 + tp; oc = oc < 0 ? 0 : (oc > 63 ? 63 : oc);
      acc += g[tp] * tile[oc][mm];
    }
    wbT[(c * 400 + m0 + mm) * 64 + o] = acc;
  }
}

// ---- k0b: Wp/Wm[(m*64+c)*64+o] = sc*(wbT[c][m][o] +/- wbT[c][nm][o])
__global__ void k0b_combine(const float* __restrict__ wbT, float* __restrict__ Wp,
                            float* __restrict__ Wm) {
  int m = blockIdx.x;
  int i = m / 20, j = m - i * 20;
  int nm = ((20 - i) % 20) * 20 + ((20 - j) % 20);
  int tid = threadIdx.x;
  const float sc = 0.5f / 16384.0f;
  for (int t = tid; t < 4096; t += 256) {
    int c = t >> 6, o = t & 63;
    float a = wbT[(c * 400 + m) * 64 + o];
    float b = wbT[(c * 400 + nm) * 64 + o];
    Wp[(m * 64 + c) * 64 + o] = (a + b) * sc;
    Wm[(m * 64 + c) * 64 + o] = (a - b) * sc;
  }
}

// ---- k12: fused forward transform + mode combine. One block per (b,c), 1024 blocks.
// Phase 1: Pw[n1][col] = sum_n2 x[n1][n2]*Tg[n2][col], written into Pm2 layout.
//   xs chunks [32][129] (pad-129: conflict-free transpose staging & broadcast reads).
//   Compute tiles: 160 threads, 4 rows x 8 cols; B = aligned float4x2 from Tg (L1).
// Phase 2: rotation fills Pm2[.][256..512); combine X1 = Lf2g . Pm2 (100 thr, 2x2).
__global__ void __launch_bounds__(256) k12(const float* __restrict__ x,
                                           const float* __restrict__ Tg,
                                           const float* __restrict__ Lf2g,
                                           float* __restrict__ X1) {
  __shared__ float xs[32][129];    // 16.5 KB
  __shared__ float Pm2[20][524];   // 41.9 KB
  __shared__ float ct[128];
  int bc = blockIdx.x, tid = threadIdx.x;
  if (tid < 128) ct[tid] = cosf(THETA * (float)tid);

  int cg = tid >> 5;          // 0..7 (active if <5)
  int rg = tid & 31;          // 0..31
  int r0 = rg * 4, c0 = cg * 8;
  bool act = (tid < 160);
  float acc[4][8];
#pragma unroll
  for (int i = 0; i < 4; ++i)
#pragma unroll
    for (int j = 0; j < 8; ++j) acc[i][j] = 0.f;

  const float* xb = x + (long)bc * 16384;
  for (int ch = 0; ch < 4; ++ch) {
    __syncthreads();
    // stage 128 n1 x 32 n2: 4096 floats, 16/thread, conflict-free (129 stride)
    for (int t = tid; t < 4096; t += 256) {
      int n1 = t >> 5, n2l = t & 31;
      xs[n2l][n1] = xb[n1 * 128 + ch * 32 + n2l];
    }
    __syncthreads();
    if (act) {
#pragma unroll 4
      for (int k = 0; k < 32; ++k) {
        const float4* tgr = (const float4*)(Tg + (ch * 32 + k) * 40 + c0);
        float4 b0 = tgr[0], b1 = tgr[1];
        float bv[8] = {b0.x, b0.y, b0.z, b0.w, b1.x, b1.y, b1.z, b1.w};
        float av[4] = {xs[k][r0], xs[k][r0 + 1], xs[k][r0 + 2], xs[k][r0 + 3]};
#pragma unroll
        for (int i = 0; i < 4; ++i)
#pragma unroll
          for (int j = 0; j < 8; ++j) acc[i][j] += av[i] * bv[j];
      }
    }
  }
  __syncthreads();
  if (act) {
#pragma unroll
    for (int j = 0; j < 8; ++j) {
      int col = c0 + j;
      int k2 = (col < 20) ? col : col - 20;
      int part = (col < 20) ? 0 : 1;
#pragma unroll
      for (int i = 0; i < 4; ++i) Pm2[k2][part * 128 + r0 + i] = acc[i][j];
    }
  }
  __syncthreads();
  // rotation: Pc1/Ps1
  for (int t = tid; t < 2560; t += 256) {
    int k2 = t >> 7, n1 = t & 127;
    float pc = Pm2[k2][n1], ps = Pm2[k2][128 + n1];
    float ck = ct[k2], sk = ct[(k2 + 96) & 127];
    Pm2[k2][256 + n1] = ck * pc - sk * ps;
    Pm2[k2][384 + n1] = sk * pc + ck * ps;
  }
  __syncthreads();
  if (tid < 100) {
    int k1 = (tid / 10) * 2, k2 = (tid % 10) * 2;
    float a00 = 0.f, a01 = 0.f, a10 = 0.f, a11 = 0.f;
    for (int t = 0; t < 512; t += 4) {
      float4 l0 = *(const float4*)(Lf2g + k1 * 512 + t);
      float4 l1 = *(const float4*)(Lf2g + (k1 + 1) * 512 + t);
      float4 p0 = *(const float4*)&Pm2[k2][t];
      float4 p1 = *(const float4*)&Pm2[k2 + 1][t];
      a00 += l0.x * p0.x + l0.y * p0.y + l0.z * p0.z + l0.w * p0.w;
      a01 += l0.x * p1.x + l0.y * p1.y + l0.z * p1.z + l0.w * p1.w;
      a10 += l1.x * p0.x + l1.y * p0.y + l1.z * p0.z + l1.w * p0.w;
      a11 += l1.x * p1.x + l1.y * p1.y + l1.z * p1.z + l1.w * p1.w;
    }
    X1[(k1 * 20 + k2) * 1024 + bc] = a00;
    X1[(k1 * 20 + k2 + 1) * 1024 + bc] = a01;
    X1[((k1 + 1) * 20 + k2) * 1024 + bc] = a10;
    X1[((k1 + 1) * 20 + k2 + 1) * 1024 + bc] = a11;
  }
}

// ---- k3 v2: grid (m*4 + bq); batch-blur folded into staging. O[(b*64+o)*400+m]
__global__ void k3_mix(const float* __restrict__ X1, const float* __restrict__ Wp,
                       const float* __restrict__ Wm, float* __restrict__ O) {
  __shared__ float Xa[4][64], Xn[4][64];
  int m = blockIdx.x >> 2, bq = blockIdx.x & 3;
  int i = m / 20, j = m - i * 20;
  int nm = ((20 - i) % 20) * 20 + ((20 - j) % 20);
  int tid = threadIdx.x;
  float g[9]; gauss9(g);
  {
    int bl = tid >> 6, c = tid & 63;
    int b = bq * 4 + bl;
    float sa = 0.f, sn = 0.f;
#pragma unroll
    for (int tp = 0; tp < 9; ++tp) {
      int bb = b - 4 + tp; bb = bb < 0 ? 0 : (bb > 15 ? 15 : bb);
      sa += g[tp] * X1[m * 1024 + bb * 64 + c];
      sn += g[tp] * X1[nm * 1024 + bb * 64 + c];
    }
    Xa[bl][c] = sa; Xn[bl][c] = sn;
  }
  __syncthreads();
  int o = tid & 63, bl = tid >> 6;
  int b = bq * 4 + bl;
  float acc = 0.f;
#pragma unroll 4
  for (int c = 0; c < 64; ++c) {
    float wp = Wp[(m * 64 + c) * 64 + o];
    float wm = Wm[(m * 64 + c) * 64 + o];
    acc += Xa[bl][c] * wp + Xn[bl][c] * wm;
  }
  O[(b * 64 + o) * 400 + m] = acc;
}

// ---- k5b: per (b,o): Rs2[42][128] (C rows 0..20, S rows 21..41), Y = L2 * Rs2
__global__ void __launch_bounds__(256) k5b_final(const float* __restrict__ O,
                                                 const float* __restrict__ L2g,
                                                 const float* __restrict__ RB2g,
                                                 float* __restrict__ out) {
  __shared__ float Os[400];
  __shared__ float Rs[42 * 128];
  int bo = blockIdx.x, tid = threadIdx.x;
  for (int t = tid; t < 400; t += 256) Os[t] = O[bo * 400 + t];
  __syncthreads();
  const float4* Bc4 = (const float4*)RB2g;             // rows 0..20
  const float4* Bs4 = (const float4*)(RB2g + 21 * 128);
  for (int task = tid; task < 1344; task += 256) {
    int r = task >> 5, vq = task & 31;
    bool isS = (r >= 21);
    int A = isS ? (r - 21) : r;
    float4 acc = make_float4(0.f, 0.f, 0.f, 0.f);
    if (A < 20) {
      const float4* Bm = isS ? Bs4 : Bc4;
      float sgn = isS ? -1.f : 1.f;
#pragma unroll
      for (int k2 = 0; k2 < 20; ++k2) {
        float ov = sgn * Os[A * 20 + k2];
        float4 b = Bm[k2 * 32 + vq];
        acc.x += ov * b.x; acc.y += ov * b.y; acc.z += ov * b.z; acc.w += ov * b.w;
      }
    }
    if (A >= 1) {
      const float4* Bm = isS ? Bc4 : Bs4;
#pragma unroll
      for (int k2 = 0; k2 < 20; ++k2) {
        float ov = Os[(A - 1) * 20 + k2];
        float4 b = Bm[(k2 + 1) * 32 + vq];
        acc.x -= ov * b.x; acc.y -= ov * b.y; acc.z -= ov * b.z; acc.w -= ov * b.w;
      }
    }
    *(float4*)&Rs[r * 128 + vq * 4] = acc;
  }
  __syncthreads();
  int ug = tid >> 4, vg = tid & 15;
  int u0 = ug * 8, v0 = vg * 4;   // v-cols: v0..v0+3 and 64+v0..64+v0+3
  float acc[8][8];
#pragma unroll
  for (int i = 0; i < 8; ++i)
#pragma unroll
    for (int j = 0; j < 8; ++j) acc[i][j] = 0.f;
  for (int r = 0; r < 42; ++r) {
    float4 a0 = *(const float4*)(L2g + r * 128 + u0);
    float4 a1 = *(const float4*)(L2g + r * 128 + u0 + 4);
    float4 b0 = *(const float4*)&Rs[r * 128 + v0];
    float4 b1 = *(const float4*)&Rs[r * 128 + 64 + v0];
    float av[8] = {a0.x, a0.y, a0.z, a0.w, a1.x, a1.y, a1.z, a1.w};
    float bv[8] = {b0.x, b0.y, b0.z, b0.w, b1.x, b1.y, b1.z, b1.w};
#pragma unroll
    for (int i = 0; i < 8; ++i)
#pragma unroll
      for (int j = 0; j < 8; ++j) acc[i][j] += av[i] * bv[j];
  }
  long base = (long)bo * 16384;
#pragma unroll
  for (int i = 0; i < 8; ++i) {
    float4 s0 = make_float4(acc[i][0], acc[i][1], acc[i][2], acc[i][3]);
    float4 s1 = make_float4(acc[i][4], acc[i][5], acc[i][6], acc[i][7]);
    *(float4*)&out[base + (u0 + i) * 128 + v0] = s0;
    *(float4*)&out[base + (u0 + i) * 128 + 64 + v0] = s1;
  }
}

extern "C" void kernel_launch(void* const* d_in, const int* in_sizes, int n_in,
                              void* d_out, int out_size, void* d_ws, size_t ws_size,
                              hipStream_t stream) {
  const float* x = (const float*)d_in[0];    // (16,64,128,128)
  const float* w1 = (const float*)d_in[1];   // (64,64,20,20)
  float* out = (float*)d_out;                // (16,64,128,128)
  float* ws = (float*)d_ws;

  float* Wp = ws;                  // 1,638,400
  float* Wm = Wp + 1638400;        // 1,638,400
  float* X1 = Wm + 1638400;        // 409,600
  float* O = X1 + 409600;          // 409,600
  float* wbT = O + 409600;         // 1,638,400
  float* Tg = wbT + 1638400;       // 5,120
  float* Lf2g = Tg + 5120;         // 10,240
  float* L2g = Lf2g + 10240;       // 5,376
  float* RB2g = L2g + 5376;        // 5,376   (total ~23 MB)

  hipLaunchKernelGGL(kinit, dim3(3), dim3(256), 0, stream, L2g, RB2g, Tg, Lf2g);
  hipLaunchKernelGGL(k0a_blurT, dim3(448), dim3(256), 0, stream, w1, wbT);
  hipLaunchKernelGGL(k0b_combine, dim3(400), dim3(256), 0, stream, wbT, Wp, Wm);
  hipLaunchKernelGGL(k12, dim3(1024), dim3(256), 0, stream, x, Tg, Lf2g, X1);
  hipLaunchKernelGGL(k3_mix, dim3(1600), dim3(256), 0, stream, X1, Wp, Wm, O);
  hipLaunchKernelGGL(k5b_final, dim3(1024), dim3(256), 0, stream, O, L2g, RB2g, out);
}